// Round 1
// baseline (403.273 us; speedup 1.0000x reference)
//
#include <hip/hip_runtime.h>

#define NQ 16384
#define NV 16384
#define DMODEL 256

typedef __bf16 bf16x8 __attribute__((ext_vector_type(8)));
typedef float f32x4 __attribute__((ext_vector_type(4)));

__device__ __forceinline__ unsigned short f2bf(float x) {
    union { float f; unsigned int u; } v; v.f = x;
    unsigned int r = v.u + 0x7fff + ((v.u >> 16) & 1);
    return (unsigned short)(r >> 16);
}
__device__ __forceinline__ float bf2f(unsigned short h) {
    union { unsigned int u; float f; } v; v.u = ((unsigned int)h) << 16;
    return v.f;
}
__device__ __forceinline__ f32x4 mfma16(bf16x8 a, bf16x8 b, f32x4 c) {
    return __builtin_amdgcn_mfma_f32_16x16x32_bf16(a, b, c, 0, 0, 0);
}

// ---------------- prep: transpose weights to bf16 [n][k] ----------------
__global__ __launch_bounds__(256) void k_prep(
    const float* __restrict__ Wv, const float* __restrict__ Woff,
    const float* __restrict__ Wattn, const float* __restrict__ Wout,
    unsigned short* __restrict__ WtV, unsigned short* __restrict__ WtC,
    unsigned short* __restrict__ WtO) {
    int t = blockIdx.x * 256 + threadIdx.x;
    if (t < 256 * 256) { int n = t >> 8, k = t & 255; WtV[t] = f2bf(Wv[k * 256 + n]); return; }
    t -= 256 * 256;
    if (t < 256 * 256) { int n = t >> 8, k = t & 255; WtO[t] = f2bf(Wout[k * 256 + n]); return; }
    t -= 256 * 256;
    if (t < 96 * 256) {
        int j = t >> 8, k = t & 255;
        float w = (j < 64) ? Woff[k * 64 + j] : Wattn[k * 32 + (j - 64)];
        WtC[j * 256 + k] = f2bf(w);
    }
}

// ---------------- LN(feat) + value GEMM -> bf16 value[b*NV+pix][256] ----------------
__global__ __launch_bounds__(256) void k_ln_value(
    const float* __restrict__ feat, const float* __restrict__ fn_scale,
    const float* __restrict__ fn_bias, const float* __restrict__ b_value,
    const unsigned short* __restrict__ WtV, unsigned short* __restrict__ value) {
    __shared__ unsigned short A[64 * 264];  // 64 rows, stride 264 bf16 (bank-stagger pad)
    const int lane = threadIdx.x & 63;
    const int w = threadIdx.x >> 6;
    const int m0 = blockIdx.x * 64;
    const float4 sc = *(const float4*)(fn_scale + lane * 4);
    const float4 bi = *(const float4*)(fn_bias + lane * 4);
    for (int r = 0; r < 16; ++r) {
        const int row = m0 + w * 16 + r;
        float4 x = *(const float4*)(feat + (size_t)row * 256 + lane * 4);
        float s = x.x + x.y + x.z + x.w;
#pragma unroll
        for (int d = 1; d < 64; d <<= 1) s += __shfl_xor(s, d);
        float mu = s * 0.00390625f;
        float d0 = x.x - mu, d1 = x.y - mu, d2 = x.z - mu, d3 = x.w - mu;
        float sq = d0 * d0 + d1 * d1 + d2 * d2 + d3 * d3;
#pragma unroll
        for (int d = 1; d < 64; d <<= 1) sq += __shfl_xor(sq, d);
        float rstd = rsqrtf(sq * 0.00390625f + 1e-6f);
        unsigned int lo = (unsigned)f2bf(d0 * rstd * sc.x + bi.x) |
                          ((unsigned)f2bf(d1 * rstd * sc.y + bi.y) << 16);
        unsigned int hi = (unsigned)f2bf(d2 * rstd * sc.z + bi.z) |
                          ((unsigned)f2bf(d3 * rstd * sc.w + bi.w) << 16);
        *(uint2*)&A[(w * 16 + r) * 264 + lane * 4] = make_uint2(lo, hi);
    }
    __syncthreads();
    const int lrow = lane & 15, lk = (lane >> 4) * 8;
    f32x4 acc[16];
#pragma unroll
    for (int nt = 0; nt < 16; ++nt) acc[nt] = (f32x4){0.f, 0.f, 0.f, 0.f};
    for (int kk = 0; kk < 8; ++kk) {
        bf16x8 a = *(const bf16x8*)&A[(w * 16 + lrow) * 264 + kk * 32 + lk];
#pragma unroll
        for (int nt = 0; nt < 16; ++nt) {
            bf16x8 b = *(const bf16x8*)(WtV + (size_t)(nt * 16 + lrow) * 256 + kk * 32 + lk);
            acc[nt] = mfma16(a, b, acc[nt]);
        }
    }
#pragma unroll
    for (int nt = 0; nt < 16; ++nt) {
        int col = nt * 16 + lrow;
        float bv = b_value[col];
#pragma unroll
        for (int r = 0; r < 4; ++r) {
            int row = m0 + w * 16 + (lane >> 4) * 4 + r;
            value[(size_t)row * 256 + col] = f2bf(acc[nt][r] + bv);
        }
    }
}

// ---------------- LN(query) + off/attn GEMM + softmax -> samples (x,y,w) ----------------
__global__ __launch_bounds__(256) void k_ln_qoff(
    const float* __restrict__ query, const float* __restrict__ qn_scale,
    const float* __restrict__ qn_bias, const float* __restrict__ refpt,
    const float* __restrict__ b_off, const float* __restrict__ b_attn,
    const unsigned short* __restrict__ WtC, float4* __restrict__ samples) {
    __shared__ unsigned short A[64 * 264];
    const int lane = threadIdx.x & 63;
    const int w = threadIdx.x >> 6;
    const int m0 = blockIdx.x * 64;
    const float4 sc = *(const float4*)(qn_scale + lane * 4);
    const float4 bi = *(const float4*)(qn_bias + lane * 4);
    for (int r = 0; r < 16; ++r) {
        const int row = m0 + w * 16 + r;
        float4 x = *(const float4*)(query + (size_t)row * 256 + lane * 4);
        float s = x.x + x.y + x.z + x.w;
#pragma unroll
        for (int d = 1; d < 64; d <<= 1) s += __shfl_xor(s, d);
        float mu = s * 0.00390625f;
        float d0 = x.x - mu, d1 = x.y - mu, d2 = x.z - mu, d3 = x.w - mu;
        float sq = d0 * d0 + d1 * d1 + d2 * d2 + d3 * d3;
#pragma unroll
        for (int d = 1; d < 64; d <<= 1) sq += __shfl_xor(sq, d);
        float rstd = rsqrtf(sq * 0.00390625f + 1e-6f);
        unsigned int lo = (unsigned)f2bf(d0 * rstd * sc.x + bi.x) |
                          ((unsigned)f2bf(d1 * rstd * sc.y + bi.y) << 16);
        unsigned int hi = (unsigned)f2bf(d2 * rstd * sc.z + bi.z) |
                          ((unsigned)f2bf(d3 * rstd * sc.w + bi.w) << 16);
        *(uint2*)&A[(w * 16 + r) * 264 + lane * 4] = make_uint2(lo, hi);
    }
    __syncthreads();
    const int lrow = lane & 15, lk = (lane >> 4) * 8;
    f32x4 acc[6];
#pragma unroll
    for (int nt = 0; nt < 6; ++nt) acc[nt] = (f32x4){0.f, 0.f, 0.f, 0.f};
    for (int kk = 0; kk < 8; ++kk) {
        bf16x8 a = *(const bf16x8*)&A[(w * 16 + lrow) * 264 + kk * 32 + lk];
#pragma unroll
        for (int nt = 0; nt < 6; ++nt) {
            bf16x8 b = *(const bf16x8*)(WtC + (size_t)(nt * 16 + lrow) * 256 + kk * 32 + lk);
            acc[nt] = mfma16(a, b, acc[nt]);
        }
    }
    __syncthreads();
    // reuse this wave's A region (16*264*2 = 8448B >= 16*96*4 = 6144B) as fp32 D buffer
    float* Dl = (float*)&A[w * 16 * 264];
#pragma unroll
    for (int nt = 0; nt < 6; ++nt) {
        int col = nt * 16 + lrow;
#pragma unroll
        for (int r = 0; r < 4; ++r) {
            Dl[((lane >> 4) * 4 + r) * 96 + col] = acc[nt][r];
        }
    }
    __syncthreads();
    for (int it = 0; it < 2; ++it) {
        int idx = it * 64 + lane;     // 16 rows x 8 heads
        int rl = idx >> 3;
        int h = idx & 7;
        int row = m0 + w * 16 + rl;
        float rx = refpt[(size_t)row * 2 + 0] * 128.f - 0.5f;
        float ry = refpt[(size_t)row * 2 + 1] * 128.f - 0.5f;
        float l0 = Dl[rl * 96 + 64 + h * 4 + 0] + b_attn[h * 4 + 0];
        float l1 = Dl[rl * 96 + 64 + h * 4 + 1] + b_attn[h * 4 + 1];
        float l2 = Dl[rl * 96 + 64 + h * 4 + 2] + b_attn[h * 4 + 2];
        float l3 = Dl[rl * 96 + 64 + h * 4 + 3] + b_attn[h * 4 + 3];
        float mx = fmaxf(fmaxf(l0, l1), fmaxf(l2, l3));
        float e0 = __expf(l0 - mx), e1 = __expf(l1 - mx);
        float e2 = __expf(l2 - mx), e3 = __expf(l3 - mx);
        float inv = 1.f / (e0 + e1 + e2 + e3);
        float ww[4] = {e0 * inv, e1 * inv, e2 * inv, e3 * inv};
#pragma unroll
        for (int p = 0; p < 4; ++p) {
            float ox = Dl[rl * 96 + h * 8 + p * 2 + 0] + b_off[h * 8 + p * 2 + 0];
            float oy = Dl[rl * 96 + h * 8 + p * 2 + 1] + b_off[h * 8 + p * 2 + 1];
            samples[((size_t)row * 8 + h) * 4 + p] = make_float4(rx + ox, ry + oy, ww[p], 0.f);
        }
    }
}

// ---------------- bilinear gather + attention-weighted sum -> bf16 acc ----------------
__global__ __launch_bounds__(256) void k_gather(
    const unsigned short* __restrict__ value, const float4* __restrict__ samples,
    unsigned short* __restrict__ accb) {
    const int tid = blockIdx.x * 256 + threadIdx.x;
    const int hd = tid & 31;
    const int t = tid >> 5;          // (b*NQ+q)*8 + h
    const int h = t & 7;
    const int bq = t >> 3;
    const int b = bq >> 14;
    const unsigned short* vb = value + ((size_t)b << 14) * 256 + h * 32 + hd;
    float a = 0.f;
#pragma unroll
    for (int p = 0; p < 4; ++p) {
        float4 s = samples[(size_t)t * 4 + p];
        float xf = floorf(s.x), yf = floorf(s.y);
        float fx = s.x - xf, fy = s.y - yf;
        int x0 = (int)xf, y0 = (int)yf;
        int x1 = x0 + 1, y1 = y0 + 1;
        float wgt = s.z;
        float w00 = (1.f - fx) * (1.f - fy) * wgt, w10 = fx * (1.f - fy) * wgt;
        float w01 = (1.f - fx) * fy * wgt,         w11 = fx * fy * wgt;
        bool bx0 = (unsigned)x0 < 128u, bx1 = (unsigned)x1 < 128u;
        bool by0 = (unsigned)y0 < 128u, by1 = (unsigned)y1 < 128u;
        int xc0 = min(max(x0, 0), 127), xc1 = min(max(x1, 0), 127);
        int yc0 = min(max(y0, 0), 127), yc1 = min(max(y1, 0), 127);
        float v00 = bf2f(vb[(size_t)(yc0 * 128 + xc0) * 256]);
        float v10 = bf2f(vb[(size_t)(yc0 * 128 + xc1) * 256]);
        float v01 = bf2f(vb[(size_t)(yc1 * 128 + xc0) * 256]);
        float v11 = bf2f(vb[(size_t)(yc1 * 128 + xc1) * 256]);
        a += v00 * ((bx0 && by0) ? w00 : 0.f);
        a += v10 * ((bx1 && by0) ? w10 : 0.f);
        a += v01 * ((bx0 && by1) ? w01 : 0.f);
        a += v11 * ((bx1 && by1) ? w11 : 0.f);
    }
    accb[(size_t)bq * 256 + h * 32 + hd] = f2bf(a);
}

// ---------------- out GEMM + bias + gated residual ----------------
__global__ __launch_bounds__(256) void k_out(
    const unsigned short* __restrict__ accb, const unsigned short* __restrict__ WtO,
    const float* __restrict__ b_out, const float* __restrict__ gamma,
    const float* __restrict__ query, float* __restrict__ out) {
    const int lane = threadIdx.x & 63;
    const int w = threadIdx.x >> 6;
    const int m0 = blockIdx.x * 128 + w * 32;
    const int lrow = lane & 15, lk = (lane >> 4) * 8;
    f32x4 acc[2][16];
#pragma unroll
    for (int mt = 0; mt < 2; ++mt)
#pragma unroll
        for (int nt = 0; nt < 16; ++nt) acc[mt][nt] = (f32x4){0.f, 0.f, 0.f, 0.f};
    for (int kk = 0; kk < 8; ++kk) {
        bf16x8 a0 = *(const bf16x8*)(accb + (size_t)(m0 + lrow) * 256 + kk * 32 + lk);
        bf16x8 a1 = *(const bf16x8*)(accb + (size_t)(m0 + 16 + lrow) * 256 + kk * 32 + lk);
#pragma unroll
        for (int nt = 0; nt < 16; ++nt) {
            bf16x8 b = *(const bf16x8*)(WtO + (size_t)(nt * 16 + lrow) * 256 + kk * 32 + lk);
            acc[0][nt] = mfma16(a0, b, acc[0][nt]);
            acc[1][nt] = mfma16(a1, b, acc[1][nt]);
        }
    }
#pragma unroll
    for (int nt = 0; nt < 16; ++nt) {
        int col = nt * 16 + lrow;
        float bo = b_out[col], g = gamma[col];
#pragma unroll
        for (int mt = 0; mt < 2; ++mt)
#pragma unroll
            for (int r = 0; r < 4; ++r) {
                size_t o = (size_t)(m0 + mt * 16 + (lane >> 4) * 4 + r) * 256 + col;
                out[o] = query[o] + g * (acc[mt][nt][r] + bo);
            }
    }
}

extern "C" void kernel_launch(void* const* d_in, const int* in_sizes, int n_in,
                              void* d_out, int out_size, void* d_ws, size_t ws_size,
                              hipStream_t stream) {
    const float* query    = (const float*)d_in[0];
    const float* feat     = (const float*)d_in[1];
    const float* refpt    = (const float*)d_in[2];
    const float* qn_scale = (const float*)d_in[5];
    const float* qn_bias  = (const float*)d_in[6];
    const float* fn_scale = (const float*)d_in[7];
    const float* fn_bias  = (const float*)d_in[8];
    const float* W_value  = (const float*)d_in[9];
    const float* b_value  = (const float*)d_in[10];
    const float* W_off    = (const float*)d_in[11];
    const float* b_off    = (const float*)d_in[12];
    const float* W_attn   = (const float*)d_in[13];
    const float* b_attn   = (const float*)d_in[14];
    const float* W_out    = (const float*)d_in[15];
    const float* b_out    = (const float*)d_in[16];
    const float* gamma    = (const float*)d_in[17];
    float* out = (float*)d_out;

    char* ws = (char*)d_ws;
    unsigned short* WtV   = (unsigned short*)(ws);
    unsigned short* WtO   = (unsigned short*)(ws + 131072);
    unsigned short* WtC   = (unsigned short*)(ws + 262144);
    unsigned short* value = (unsigned short*)(ws + 311296);
    float4*        samples = (float4*)(ws + 311296 + 33554432);
    unsigned short* accb  = (unsigned short*)(ws + 311296 + 67108864);

    hipLaunchKernelGGL(k_prep, dim3(608), dim3(256), 0, stream,
                       W_value, W_off, W_attn, W_out, WtV, WtC, WtO);
    hipLaunchKernelGGL(k_ln_value, dim3(1024), dim3(256), 0, stream,
                       feat, fn_scale, fn_bias, b_value, WtV, value);
    hipLaunchKernelGGL(k_ln_qoff, dim3(1024), dim3(256), 0, stream,
                       query, qn_scale, qn_bias, refpt, b_off, b_attn, WtC, samples);
    hipLaunchKernelGGL(k_gather, dim3(65536), dim3(256), 0, stream,
                       value, samples, accb);
    hipLaunchKernelGGL(k_out, dim3(512), dim3(256), 0, stream,
                       accb, WtO, b_out, gamma, query, out);
}

// Round 2
// 279.880 us; speedup vs baseline: 1.4409x; 1.4409x over previous
//
#include <hip/hip_runtime.h>

#define NQ 16384
#define NV 16384
#define DMODEL 256

typedef __bf16 bf16x8 __attribute__((ext_vector_type(8)));
typedef float f32x4 __attribute__((ext_vector_type(4)));

__device__ __forceinline__ unsigned short f2bf(float x) {
    union { float f; unsigned int u; } v; v.f = x;
    unsigned int r = v.u + 0x7fff + ((v.u >> 16) & 1);
    return (unsigned short)(r >> 16);
}
__device__ __forceinline__ float bf2f(unsigned short h) {
    union { unsigned int u; float f; } v; v.u = ((unsigned int)h) << 16;
    return v.f;
}
// low bf16 of a uint -> float (shift into exponent position)
__device__ __forceinline__ float blo(unsigned int u) {
    union { unsigned int u; float f; } v; v.u = u << 16; return v.f;
}
// high bf16 of a uint -> float (mask only)
__device__ __forceinline__ float bhi(unsigned int u) {
    union { unsigned int u; float f; } v; v.u = u & 0xFFFF0000u; return v.f;
}
__device__ __forceinline__ f32x4 mfma16(bf16x8 a, bf16x8 b, f32x4 c) {
    return __builtin_amdgcn_mfma_f32_16x16x32_bf16(a, b, c, 0, 0, 0);
}

// ---------------- prep: transpose weights to bf16 [n][k] ----------------
__global__ __launch_bounds__(256) void k_prep(
    const float* __restrict__ Wv, const float* __restrict__ Woff,
    const float* __restrict__ Wattn, const float* __restrict__ Wout,
    unsigned short* __restrict__ WtV, unsigned short* __restrict__ WtC,
    unsigned short* __restrict__ WtO) {
    int t = blockIdx.x * 256 + threadIdx.x;
    if (t < 256 * 256) { int n = t >> 8, k = t & 255; WtV[t] = f2bf(Wv[k * 256 + n]); return; }
    t -= 256 * 256;
    if (t < 256 * 256) { int n = t >> 8, k = t & 255; WtO[t] = f2bf(Wout[k * 256 + n]); return; }
    t -= 256 * 256;
    if (t < 96 * 256) {
        int j = t >> 8, k = t & 255;
        float w = (j < 64) ? Woff[k * 64 + j] : Wattn[k * 32 + (j - 64)];
        WtC[j * 256 + k] = f2bf(w);
    }
}

// ---------------- LN(feat) + value GEMM -> bf16 value[b*NV+pix][256] ----------------
__global__ __launch_bounds__(256) void k_ln_value(
    const float* __restrict__ feat, const float* __restrict__ fn_scale,
    const float* __restrict__ fn_bias, const float* __restrict__ b_value,
    const unsigned short* __restrict__ WtV, unsigned short* __restrict__ value) {
    __shared__ unsigned short A[64 * 264];  // 64 rows, stride 264 bf16 (bank-stagger pad)
    const int lane = threadIdx.x & 63;
    const int w = threadIdx.x >> 6;
    const int m0 = blockIdx.x * 64;
    const float4 sc = *(const float4*)(fn_scale + lane * 4);
    const float4 bi = *(const float4*)(fn_bias + lane * 4);
    for (int r = 0; r < 16; ++r) {
        const int row = m0 + w * 16 + r;
        float4 x = *(const float4*)(feat + (size_t)row * 256 + lane * 4);
        float s = x.x + x.y + x.z + x.w;
        float sq = x.x * x.x + x.y * x.y + x.z * x.z + x.w * x.w;
#pragma unroll
        for (int d = 1; d < 64; d <<= 1) {   // two independent chains, interleaved
            s += __shfl_xor(s, d);
            sq += __shfl_xor(sq, d);
        }
        float mu = s * 0.00390625f;
        float var = sq * 0.00390625f - mu * mu;
        float rstd = rsqrtf(var + 1e-6f);
        float d0 = x.x - mu, d1 = x.y - mu, d2 = x.z - mu, d3 = x.w - mu;
        unsigned int lo = (unsigned)f2bf(d0 * rstd * sc.x + bi.x) |
                          ((unsigned)f2bf(d1 * rstd * sc.y + bi.y) << 16);
        unsigned int hi = (unsigned)f2bf(d2 * rstd * sc.z + bi.z) |
                          ((unsigned)f2bf(d3 * rstd * sc.w + bi.w) << 16);
        *(uint2*)&A[(w * 16 + r) * 264 + lane * 4] = make_uint2(lo, hi);
    }
    __syncthreads();
    const int lrow = lane & 15, lk = (lane >> 4) * 8;
    f32x4 acc[16];
#pragma unroll
    for (int nt = 0; nt < 16; ++nt) acc[nt] = (f32x4){0.f, 0.f, 0.f, 0.f};
    for (int kk = 0; kk < 8; ++kk) {
        bf16x8 a = *(const bf16x8*)&A[(w * 16 + lrow) * 264 + kk * 32 + lk];
#pragma unroll
        for (int nt = 0; nt < 16; ++nt) {
            bf16x8 b = *(const bf16x8*)(WtV + (size_t)(nt * 16 + lrow) * 256 + kk * 32 + lk);
            acc[nt] = mfma16(a, b, acc[nt]);
        }
    }
#pragma unroll
    for (int nt = 0; nt < 16; ++nt) {
        int col = nt * 16 + lrow;
        float bv = b_value[col];
#pragma unroll
        for (int r = 0; r < 4; ++r) {
            int row = m0 + w * 16 + (lane >> 4) * 4 + r;
            value[(size_t)row * 256 + col] = f2bf(acc[nt][r] + bv);
        }
    }
}

// ---------------- LN(query) + off/attn GEMM + softmax -> samples (x,y,w) ----------------
__global__ __launch_bounds__(256) void k_ln_qoff(
    const float* __restrict__ query, const float* __restrict__ qn_scale,
    const float* __restrict__ qn_bias, const float* __restrict__ refpt,
    const float* __restrict__ b_off, const float* __restrict__ b_attn,
    const unsigned short* __restrict__ WtC, float4* __restrict__ samples) {
    __shared__ unsigned short A[64 * 264];
    const int lane = threadIdx.x & 63;
    const int w = threadIdx.x >> 6;
    const int m0 = blockIdx.x * 64;
    const float4 sc = *(const float4*)(qn_scale + lane * 4);
    const float4 bi = *(const float4*)(qn_bias + lane * 4);
    for (int r = 0; r < 16; ++r) {
        const int row = m0 + w * 16 + r;
        float4 x = *(const float4*)(query + (size_t)row * 256 + lane * 4);
        float s = x.x + x.y + x.z + x.w;
        float sq = x.x * x.x + x.y * x.y + x.z * x.z + x.w * x.w;
#pragma unroll
        for (int d = 1; d < 64; d <<= 1) {
            s += __shfl_xor(s, d);
            sq += __shfl_xor(sq, d);
        }
        float mu = s * 0.00390625f;
        float var = sq * 0.00390625f - mu * mu;
        float rstd = rsqrtf(var + 1e-6f);
        float d0 = x.x - mu, d1 = x.y - mu, d2 = x.z - mu, d3 = x.w - mu;
        unsigned int lo = (unsigned)f2bf(d0 * rstd * sc.x + bi.x) |
                          ((unsigned)f2bf(d1 * rstd * sc.y + bi.y) << 16);
        unsigned int hi = (unsigned)f2bf(d2 * rstd * sc.z + bi.z) |
                          ((unsigned)f2bf(d3 * rstd * sc.w + bi.w) << 16);
        *(uint2*)&A[(w * 16 + r) * 264 + lane * 4] = make_uint2(lo, hi);
    }
    __syncthreads();
    const int lrow = lane & 15, lk = (lane >> 4) * 8;
    f32x4 acc[6];
#pragma unroll
    for (int nt = 0; nt < 6; ++nt) acc[nt] = (f32x4){0.f, 0.f, 0.f, 0.f};
    for (int kk = 0; kk < 8; ++kk) {
        bf16x8 a = *(const bf16x8*)&A[(w * 16 + lrow) * 264 + kk * 32 + lk];
#pragma unroll
        for (int nt = 0; nt < 6; ++nt) {
            bf16x8 b = *(const bf16x8*)(WtC + (size_t)(nt * 16 + lrow) * 256 + kk * 32 + lk);
            acc[nt] = mfma16(a, b, acc[nt]);
        }
    }
    __syncthreads();
    // reuse this wave's A region (16*264*2 = 8448B >= 16*96*4 = 6144B) as fp32 D buffer
    float* Dl = (float*)&A[w * 16 * 264];
#pragma unroll
    for (int nt = 0; nt < 6; ++nt) {
        int col = nt * 16 + lrow;
#pragma unroll
        for (int r = 0; r < 4; ++r) {
            Dl[((lane >> 4) * 4 + r) * 96 + col] = acc[nt][r];
        }
    }
    __syncthreads();
    for (int it = 0; it < 2; ++it) {
        int idx = it * 64 + lane;     // 16 rows x 8 heads
        int rl = idx >> 3;
        int h = idx & 7;
        int row = m0 + w * 16 + rl;
        float rx = refpt[(size_t)row * 2 + 0] * 128.f - 0.5f;
        float ry = refpt[(size_t)row * 2 + 1] * 128.f - 0.5f;
        float l0 = Dl[rl * 96 + 64 + h * 4 + 0] + b_attn[h * 4 + 0];
        float l1 = Dl[rl * 96 + 64 + h * 4 + 1] + b_attn[h * 4 + 1];
        float l2 = Dl[rl * 96 + 64 + h * 4 + 2] + b_attn[h * 4 + 2];
        float l3 = Dl[rl * 96 + 64 + h * 4 + 3] + b_attn[h * 4 + 3];
        float mx = fmaxf(fmaxf(l0, l1), fmaxf(l2, l3));
        float e0 = __expf(l0 - mx), e1 = __expf(l1 - mx);
        float e2 = __expf(l2 - mx), e3 = __expf(l3 - mx);
        float inv = 1.f / (e0 + e1 + e2 + e3);
        float ww[4] = {e0 * inv, e1 * inv, e2 * inv, e3 * inv};
#pragma unroll
        for (int p = 0; p < 4; ++p) {
            float ox = Dl[rl * 96 + h * 8 + p * 2 + 0] + b_off[h * 8 + p * 2 + 0];
            float oy = Dl[rl * 96 + h * 8 + p * 2 + 1] + b_off[h * 8 + p * 2 + 1];
            samples[((size_t)row * 8 + h) * 4 + p] = make_float4(rx + ox, ry + oy, ww[p], 0.f);
        }
    }
}

// ---------------- bilinear gather + attention-weighted sum -> bf16 acc ----------------
// 4 lanes per (b,q,h); each lane owns 8 channels, loads 16B (uint4) per tap.
__global__ __launch_bounds__(256) void k_gather(
    const unsigned short* __restrict__ value, const float4* __restrict__ samples,
    unsigned short* __restrict__ accb) {
    const int tid = blockIdx.x * 256 + threadIdx.x;
    const int sub = tid & 3;         // channel-quad (8 channels)
    const int t = tid >> 2;          // (b*NQ+q)*8 + h
    const int h = t & 7;
    const int bq = t >> 3;
    const int b = bq >> 14;
    const unsigned short* vb = value + ((size_t)b << 14) * 256 + h * 32 + sub * 8;
    float a0 = 0.f, a1 = 0.f, a2 = 0.f, a3 = 0.f;
    float a4 = 0.f, a5 = 0.f, a6 = 0.f, a7 = 0.f;
#pragma unroll
    for (int p = 0; p < 4; ++p) {
        float4 s = samples[(size_t)t * 4 + p];
        float xf = floorf(s.x), yf = floorf(s.y);
        float fx = s.x - xf, fy = s.y - yf;
        int x0 = (int)xf, y0 = (int)yf;
        int x1 = x0 + 1, y1 = y0 + 1;
        float wgt = s.z;
        bool bx0 = (unsigned)x0 < 128u, bx1 = (unsigned)x1 < 128u;
        bool by0 = (unsigned)y0 < 128u, by1 = (unsigned)y1 < 128u;
        float wt[4];
        wt[0] = (bx0 && by0) ? (1.f - fx) * (1.f - fy) * wgt : 0.f;
        wt[1] = (bx1 && by0) ? fx * (1.f - fy) * wgt : 0.f;
        wt[2] = (bx0 && by1) ? (1.f - fx) * fy * wgt : 0.f;
        wt[3] = (bx1 && by1) ? fx * fy * wgt : 0.f;
        int xc0 = min(max(x0, 0), 127), xc1 = min(max(x1, 0), 127);
        int yc0 = min(max(y0, 0), 127), yc1 = min(max(y1, 0), 127);
        int pix[4];
        pix[0] = yc0 * 128 + xc0; pix[1] = yc0 * 128 + xc1;
        pix[2] = yc1 * 128 + xc0; pix[3] = yc1 * 128 + xc1;
#pragma unroll
        for (int tp = 0; tp < 4; ++tp) {
            uint4 u = *(const uint4*)(vb + (size_t)pix[tp] * 256);
            float w = wt[tp];
            a0 = fmaf(w, blo(u.x), a0); a1 = fmaf(w, bhi(u.x), a1);
            a2 = fmaf(w, blo(u.y), a2); a3 = fmaf(w, bhi(u.y), a3);
            a4 = fmaf(w, blo(u.z), a4); a5 = fmaf(w, bhi(u.z), a5);
            a6 = fmaf(w, blo(u.w), a6); a7 = fmaf(w, bhi(u.w), a7);
        }
    }
    uint4 r;
    r.x = (unsigned)f2bf(a0) | ((unsigned)f2bf(a1) << 16);
    r.y = (unsigned)f2bf(a2) | ((unsigned)f2bf(a3) << 16);
    r.z = (unsigned)f2bf(a4) | ((unsigned)f2bf(a5) << 16);
    r.w = (unsigned)f2bf(a6) | ((unsigned)f2bf(a7) << 16);
    *(uint4*)(accb + (size_t)bq * 256 + h * 32 + sub * 8) = r;
}

// ---------------- out GEMM + bias + gated residual ----------------
__global__ __launch_bounds__(256) void k_out(
    const unsigned short* __restrict__ accb, const unsigned short* __restrict__ WtO,
    const float* __restrict__ b_out, const float* __restrict__ gamma,
    const float* __restrict__ query, float* __restrict__ out) {
    const int lane = threadIdx.x & 63;
    const int w = threadIdx.x >> 6;
    const int m0 = blockIdx.x * 128 + w * 32;
    const int lrow = lane & 15, lk = (lane >> 4) * 8;
    f32x4 acc[2][16];
#pragma unroll
    for (int mt = 0; mt < 2; ++mt)
#pragma unroll
        for (int nt = 0; nt < 16; ++nt) acc[mt][nt] = (f32x4){0.f, 0.f, 0.f, 0.f};
    for (int kk = 0; kk < 8; ++kk) {
        bf16x8 a0 = *(const bf16x8*)(accb + (size_t)(m0 + lrow) * 256 + kk * 32 + lk);
        bf16x8 a1 = *(const bf16x8*)(accb + (size_t)(m0 + 16 + lrow) * 256 + kk * 32 + lk);
#pragma unroll
        for (int nt = 0; nt < 16; ++nt) {
            bf16x8 b = *(const bf16x8*)(WtO + (size_t)(nt * 16 + lrow) * 256 + kk * 32 + lk);
            acc[0][nt] = mfma16(a0, b, acc[0][nt]);
            acc[1][nt] = mfma16(a1, b, acc[1][nt]);
        }
    }
#pragma unroll
    for (int nt = 0; nt < 16; ++nt) {
        int col = nt * 16 + lrow;
        float bo = b_out[col], g = gamma[col];
#pragma unroll
        for (int mt = 0; mt < 2; ++mt)
#pragma unroll
            for (int r = 0; r < 4; ++r) {
                size_t o = (size_t)(m0 + mt * 16 + (lane >> 4) * 4 + r) * 256 + col;
                out[o] = query[o] + g * (acc[mt][nt][r] + bo);
            }
    }
}

extern "C" void kernel_launch(void* const* d_in, const int* in_sizes, int n_in,
                              void* d_out, int out_size, void* d_ws, size_t ws_size,
                              hipStream_t stream) {
    const float* query    = (const float*)d_in[0];
    const float* feat     = (const float*)d_in[1];
    const float* refpt    = (const float*)d_in[2];
    const float* qn_scale = (const float*)d_in[5];
    const float* qn_bias  = (const float*)d_in[6];
    const float* fn_scale = (const float*)d_in[7];
    const float* fn_bias  = (const float*)d_in[8];
    const float* W_value  = (const float*)d_in[9];
    const float* b_value  = (const float*)d_in[10];
    const float* W_off    = (const float*)d_in[11];
    const float* b_off    = (const float*)d_in[12];
    const float* W_attn   = (const float*)d_in[13];
    const float* b_attn   = (const float*)d_in[14];
    const float* W_out    = (const float*)d_in[15];
    const float* b_out    = (const float*)d_in[16];
    const float* gamma    = (const float*)d_in[17];
    float* out = (float*)d_out;

    char* ws = (char*)d_ws;
    unsigned short* WtV   = (unsigned short*)(ws);
    unsigned short* WtO   = (unsigned short*)(ws + 131072);
    unsigned short* WtC   = (unsigned short*)(ws + 262144);
    unsigned short* value = (unsigned short*)(ws + 311296);
    float4*        samples = (float4*)(ws + 311296 + 33554432);
    unsigned short* accb  = (unsigned short*)(ws + 311296 + 67108864);

    hipLaunchKernelGGL(k_prep, dim3(608), dim3(256), 0, stream,
                       W_value, W_off, W_attn, W_out, WtV, WtC, WtO);
    hipLaunchKernelGGL(k_ln_value, dim3(1024), dim3(256), 0, stream,
                       feat, fn_scale, fn_bias, b_value, WtV, value);
    hipLaunchKernelGGL(k_ln_qoff, dim3(1024), dim3(256), 0, stream,
                       query, qn_scale, qn_bias, refpt, b_off, b_attn, WtC, samples);
    hipLaunchKernelGGL(k_gather, dim3(8192), dim3(256), 0, stream,
                       value, samples, accb);
    hipLaunchKernelGGL(k_out, dim3(512), dim3(256), 0, stream,
                       accb, WtO, b_out, gamma, query, out);
}

// Round 3
// 244.094 us; speedup vs baseline: 1.6521x; 1.1466x over previous
//
#include <hip/hip_runtime.h>

#define NQ 16384
#define NV 16384
#define DMODEL 256

typedef __bf16 bf16x8 __attribute__((ext_vector_type(8)));
typedef float f32x4 __attribute__((ext_vector_type(4)));

__device__ __forceinline__ unsigned short f2bf(float x) {
    union { float f; unsigned int u; } v; v.f = x;
    unsigned int r = v.u + 0x7fff + ((v.u >> 16) & 1);
    return (unsigned short)(r >> 16);
}
__device__ __forceinline__ float bf2f(unsigned short h) {
    union { unsigned int u; float f; } v; v.u = ((unsigned int)h) << 16;
    return v.f;
}
__device__ __forceinline__ float blo(unsigned int u) {
    union { unsigned int u; float f; } v; v.u = u << 16; return v.f;
}
__device__ __forceinline__ float bhi(unsigned int u) {
    union { unsigned int u; float f; } v; v.u = u & 0xFFFF0000u; return v.f;
}
__device__ __forceinline__ f32x4 mfma16(bf16x8 a, bf16x8 b, f32x4 c) {
    return __builtin_amdgcn_mfma_f32_16x16x32_bf16(a, b, c, 0, 0, 0);
}

// LN staging: 16-lane row groups, 4 rows per wave per step, all loads upfront.
// Writes 64 rows (w*16..w*16+15 per wave) of bf16 into A with ushort stride 264.
__device__ __forceinline__ void ln_stage(
    const float* __restrict__ src, const float* __restrict__ scale,
    const float* __restrict__ bias, unsigned short* A, int m0, int w, int lane) {
    const int g = lane >> 4;    // row within quad
    const int li = lane & 15;   // 16-float segment
    float4 sc[4], bi[4];
#pragma unroll
    for (int j = 0; j < 4; ++j) {
        sc[j] = *(const float4*)(scale + li * 16 + j * 4);
        bi[j] = *(const float4*)(bias + li * 16 + j * 4);
    }
    float4 x[4][4];
#pragma unroll
    for (int it = 0; it < 4; ++it) {
        const size_t row = (size_t)(m0 + w * 16 + it * 4 + g);
#pragma unroll
        for (int j = 0; j < 4; ++j)
            x[it][j] = *(const float4*)(src + row * 256 + li * 16 + j * 4);
    }
#pragma unroll
    for (int it = 0; it < 4; ++it) {
        float s = 0.f, sq = 0.f;
#pragma unroll
        for (int j = 0; j < 4; ++j) {
            s  += x[it][j].x + x[it][j].y + x[it][j].z + x[it][j].w;
            sq += x[it][j].x * x[it][j].x + x[it][j].y * x[it][j].y +
                  x[it][j].z * x[it][j].z + x[it][j].w * x[it][j].w;
        }
#pragma unroll
        for (int d = 1; d < 16; d <<= 1) {
            s  += __shfl_xor(s, d);
            sq += __shfl_xor(sq, d);
        }
        float mu = s * 0.00390625f;
        float rstd = rsqrtf(sq * 0.00390625f - mu * mu + 1e-6f);
        unsigned int pk[8];
#pragma unroll
        for (int j = 0; j < 4; ++j) {
            pk[2 * j] = (unsigned)f2bf((x[it][j].x - mu) * rstd * sc[j].x + bi[j].x) |
                        ((unsigned)f2bf((x[it][j].y - mu) * rstd * sc[j].y + bi[j].y) << 16);
            pk[2 * j + 1] = (unsigned)f2bf((x[it][j].z - mu) * rstd * sc[j].z + bi[j].z) |
                            ((unsigned)f2bf((x[it][j].w - mu) * rstd * sc[j].w + bi[j].w) << 16);
        }
        uint4* dst = (uint4*)&A[(w * 16 + it * 4 + g) * 264 + li * 16];
        dst[0] = make_uint4(pk[0], pk[1], pk[2], pk[3]);
        dst[1] = make_uint4(pk[4], pk[5], pk[6], pk[7]);
    }
}

// ---------------- prep: transpose weights to bf16 [n][k] ----------------
__global__ __launch_bounds__(256) void k_prep(
    const float* __restrict__ Wv, const float* __restrict__ Woff,
    const float* __restrict__ Wattn, const float* __restrict__ Wout,
    unsigned short* __restrict__ WtV, unsigned short* __restrict__ WtC,
    unsigned short* __restrict__ WtO) {
    int t = blockIdx.x * 256 + threadIdx.x;
    if (t < 256 * 256) { int n = t >> 8, k = t & 255; WtV[t] = f2bf(Wv[k * 256 + n]); return; }
    t -= 256 * 256;
    if (t < 256 * 256) { int n = t >> 8, k = t & 255; WtO[t] = f2bf(Wout[k * 256 + n]); return; }
    t -= 256 * 256;
    if (t < 96 * 256) {
        int j = t >> 8, k = t & 255;
        float w = (j < 64) ? Woff[k * 64 + j] : Wattn[k * 32 + (j - 64)];
        WtC[j * 256 + k] = f2bf(w);
    }
}

// ---------------- LN(feat) + value GEMM -> bf16 value ----------------
__global__ __launch_bounds__(256) void k_ln_value(
    const float* __restrict__ feat, const float* __restrict__ fn_scale,
    const float* __restrict__ fn_bias, const float* __restrict__ b_value,
    const unsigned short* __restrict__ WtV, unsigned short* __restrict__ value) {
    __shared__ unsigned short A[64 * 264];
    const int lane = threadIdx.x & 63;
    const int w = threadIdx.x >> 6;
    const int m0 = blockIdx.x * 64;
    ln_stage(feat, fn_scale, fn_bias, A, m0, w, lane);
    __syncthreads();
    const int lrow = lane & 15, lk = (lane >> 4) * 8;
    f32x4 acc[16];
#pragma unroll
    for (int nt = 0; nt < 16; ++nt) acc[nt] = (f32x4){0.f, 0.f, 0.f, 0.f};
    for (int kk = 0; kk < 8; ++kk) {
        bf16x8 a = *(const bf16x8*)&A[(w * 16 + lrow) * 264 + kk * 32 + lk];
#pragma unroll
        for (int nt = 0; nt < 16; ++nt) {
            bf16x8 b = *(const bf16x8*)(WtV + (size_t)(nt * 16 + lrow) * 256 + kk * 32 + lk);
            acc[nt] = mfma16(a, b, acc[nt]);
        }
    }
#pragma unroll
    for (int nt = 0; nt < 16; ++nt) {
        int col = nt * 16 + lrow;
        float bv = b_value[col];
#pragma unroll
        for (int r = 0; r < 4; ++r) {
            int row = m0 + w * 16 + (lane >> 4) * 4 + r;
            value[(size_t)row * 256 + col] = f2bf(acc[nt][r] + bv);
        }
    }
}

// ---------------- LN(query) + off/attn GEMM + softmax -> samples ----------------
__global__ __launch_bounds__(256) void k_ln_qoff(
    const float* __restrict__ query, const float* __restrict__ qn_scale,
    const float* __restrict__ qn_bias, const float* __restrict__ refpt,
    const float* __restrict__ b_off, const float* __restrict__ b_attn,
    const unsigned short* __restrict__ WtC, float4* __restrict__ samples) {
    __shared__ unsigned short A[64 * 264];
    const int lane = threadIdx.x & 63;
    const int w = threadIdx.x >> 6;
    const int m0 = blockIdx.x * 64;
    ln_stage(query, qn_scale, qn_bias, A, m0, w, lane);
    __syncthreads();
    const int lrow = lane & 15, lk = (lane >> 4) * 8;
    f32x4 acc[6];
#pragma unroll
    for (int nt = 0; nt < 6; ++nt) acc[nt] = (f32x4){0.f, 0.f, 0.f, 0.f};
    for (int kk = 0; kk < 8; ++kk) {
        bf16x8 a = *(const bf16x8*)&A[(w * 16 + lrow) * 264 + kk * 32 + lk];
#pragma unroll
        for (int nt = 0; nt < 6; ++nt) {
            bf16x8 b = *(const bf16x8*)(WtC + (size_t)(nt * 16 + lrow) * 256 + kk * 32 + lk);
            acc[nt] = mfma16(a, b, acc[nt]);
        }
    }
    __syncthreads();
    // reuse this wave's A region (16*264*2 = 8448B >= 16*96*4 = 6144B) as fp32 D buffer
    float* Dl = (float*)&A[w * 16 * 264];
#pragma unroll
    for (int nt = 0; nt < 6; ++nt) {
        int col = nt * 16 + lrow;
#pragma unroll
        for (int r = 0; r < 4; ++r) {
            Dl[((lane >> 4) * 4 + r) * 96 + col] = acc[nt][r];
        }
    }
    __syncthreads();
    for (int it = 0; it < 2; ++it) {
        int idx = it * 64 + lane;     // 16 rows x 8 heads
        int rl = idx >> 3;
        int h = idx & 7;
        int row = m0 + w * 16 + rl;
        float rx = refpt[(size_t)row * 2 + 0] * 128.f - 0.5f;
        float ry = refpt[(size_t)row * 2 + 1] * 128.f - 0.5f;
        float l0 = Dl[rl * 96 + 64 + h * 4 + 0] + b_attn[h * 4 + 0];
        float l1 = Dl[rl * 96 + 64 + h * 4 + 1] + b_attn[h * 4 + 1];
        float l2 = Dl[rl * 96 + 64 + h * 4 + 2] + b_attn[h * 4 + 2];
        float l3 = Dl[rl * 96 + 64 + h * 4 + 3] + b_attn[h * 4 + 3];
        float mx = fmaxf(fmaxf(l0, l1), fmaxf(l2, l3));
        float e0 = __expf(l0 - mx), e1 = __expf(l1 - mx);
        float e2 = __expf(l2 - mx), e3 = __expf(l3 - mx);
        float inv = 1.f / (e0 + e1 + e2 + e3);
        float ww[4] = {e0 * inv, e1 * inv, e2 * inv, e3 * inv};
#pragma unroll
        for (int p = 0; p < 4; ++p) {
            float ox = Dl[rl * 96 + h * 8 + p * 2 + 0] + b_off[h * 8 + p * 2 + 0];
            float oy = Dl[rl * 96 + h * 8 + p * 2 + 1] + b_off[h * 8 + p * 2 + 1];
            samples[((size_t)row * 8 + h) * 4 + p] = make_float4(rx + ox, ry + oy, ww[p], 0.f);
        }
    }
}

// ---------------- bilinear gather + attention-weighted sum -> bf16 acc ----------------
// 4 lanes per (b,q,h); each lane owns 8 channels, loads 16B (uint4) per tap.
__global__ __launch_bounds__(256) void k_gather(
    const unsigned short* __restrict__ value, const float4* __restrict__ samples,
    unsigned short* __restrict__ accb) {
    const int tid = blockIdx.x * 256 + threadIdx.x;
    const int sub = tid & 3;         // channel-quad (8 channels)
    const int t = tid >> 2;          // (b*NQ+q)*8 + h
    const int h = t & 7;
    const int bq = t >> 3;
    const int b = bq >> 14;
    const unsigned short* vb = value + ((size_t)b << 14) * 256 + h * 32 + sub * 8;
    float a0 = 0.f, a1 = 0.f, a2 = 0.f, a3 = 0.f;
    float a4 = 0.f, a5 = 0.f, a6 = 0.f, a7 = 0.f;
#pragma unroll
    for (int p = 0; p < 4; ++p) {
        float4 s = samples[(size_t)t * 4 + p];
        float xf = floorf(s.x), yf = floorf(s.y);
        float fx = s.x - xf, fy = s.y - yf;
        int x0 = (int)xf, y0 = (int)yf;
        int x1 = x0 + 1, y1 = y0 + 1;
        float wgt = s.z;
        bool bx0 = (unsigned)x0 < 128u, bx1 = (unsigned)x1 < 128u;
        bool by0 = (unsigned)y0 < 128u, by1 = (unsigned)y1 < 128u;
        float wt[4];
        wt[0] = (bx0 && by0) ? (1.f - fx) * (1.f - fy) * wgt : 0.f;
        wt[1] = (bx1 && by0) ? fx * (1.f - fy) * wgt : 0.f;
        wt[2] = (bx0 && by1) ? (1.f - fx) * fy * wgt : 0.f;
        wt[3] = (bx1 && by1) ? fx * fy * wgt : 0.f;
        int xc0 = min(max(x0, 0), 127), xc1 = min(max(x1, 0), 127);
        int yc0 = min(max(y0, 0), 127), yc1 = min(max(y1, 0), 127);
        int pix[4];
        pix[0] = yc0 * 128 + xc0; pix[1] = yc0 * 128 + xc1;
        pix[2] = yc1 * 128 + xc0; pix[3] = yc1 * 128 + xc1;
#pragma unroll
        for (int tp = 0; tp < 4; ++tp) {
            uint4 u = *(const uint4*)(vb + (size_t)pix[tp] * 256);
            float w = wt[tp];
            a0 = fmaf(w, blo(u.x), a0); a1 = fmaf(w, bhi(u.x), a1);
            a2 = fmaf(w, blo(u.y), a2); a3 = fmaf(w, bhi(u.y), a3);
            a4 = fmaf(w, blo(u.z), a4); a5 = fmaf(w, bhi(u.z), a5);
            a6 = fmaf(w, blo(u.w), a6); a7 = fmaf(w, bhi(u.w), a7);
        }
    }
    uint4 r;
    r.x = (unsigned)f2bf(a0) | ((unsigned)f2bf(a1) << 16);
    r.y = (unsigned)f2bf(a2) | ((unsigned)f2bf(a3) << 16);
    r.z = (unsigned)f2bf(a4) | ((unsigned)f2bf(a5) << 16);
    r.w = (unsigned)f2bf(a6) | ((unsigned)f2bf(a7) << 16);
    *(uint4*)(accb + (size_t)bq * 256 + h * 32 + sub * 8) = r;
}

// ---------------- out GEMM + bias + gated residual ----------------
__global__ __launch_bounds__(256) void k_out(
    const unsigned short* __restrict__ accb, const unsigned short* __restrict__ WtO,
    const float* __restrict__ b_out, const float* __restrict__ gamma,
    const float* __restrict__ query, float* __restrict__ out) {
    const int lane = threadIdx.x & 63;
    const int w = threadIdx.x >> 6;
    const int m0 = blockIdx.x * 128 + w * 32;
    const int lrow = lane & 15, lk = (lane >> 4) * 8;
    f32x4 acc[2][16];
#pragma unroll
    for (int mt = 0; mt < 2; ++mt)
#pragma unroll
        for (int nt = 0; nt < 16; ++nt) acc[mt][nt] = (f32x4){0.f, 0.f, 0.f, 0.f};
    for (int kk = 0; kk < 8; ++kk) {
        bf16x8 a0 = *(const bf16x8*)(accb + (size_t)(m0 + lrow) * 256 + kk * 32 + lk);
        bf16x8 a1 = *(const bf16x8*)(accb + (size_t)(m0 + 16 + lrow) * 256 + kk * 32 + lk);
#pragma unroll
        for (int nt = 0; nt < 16; ++nt) {
            bf16x8 b = *(const bf16x8*)(WtO + (size_t)(nt * 16 + lrow) * 256 + kk * 32 + lk);
            acc[0][nt] = mfma16(a0, b, acc[0][nt]);
            acc[1][nt] = mfma16(a1, b, acc[1][nt]);
        }
    }
#pragma unroll
    for (int nt = 0; nt < 16; ++nt) {
        int col = nt * 16 + lrow;
        float bo = b_out[col], g = gamma[col];
#pragma unroll
        for (int mt = 0; mt < 2; ++mt)
#pragma unroll
            for (int r = 0; r < 4; ++r) {
                size_t o = (size_t)(m0 + mt * 16 + (lane >> 4) * 4 + r) * 256 + col;
                out[o] = query[o] + g * (acc[mt][nt][r] + bo);
            }
    }
}

extern "C" void kernel_launch(void* const* d_in, const int* in_sizes, int n_in,
                              void* d_out, int out_size, void* d_ws, size_t ws_size,
                              hipStream_t stream) {
    const float* query    = (const float*)d_in[0];
    const float* feat     = (const float*)d_in[1];
    const float* refpt    = (const float*)d_in[2];
    const float* qn_scale = (const float*)d_in[5];
    const float* qn_bias  = (const float*)d_in[6];
    const float* fn_scale = (const float*)d_in[7];
    const float* fn_bias  = (const float*)d_in[8];
    const float* W_value  = (const float*)d_in[9];
    const float* b_value  = (const float*)d_in[10];
    const float* W_off    = (const float*)d_in[11];
    const float* b_off    = (const float*)d_in[12];
    const float* W_attn   = (const float*)d_in[13];
    const float* b_attn   = (const float*)d_in[14];
    const float* W_out    = (const float*)d_in[15];
    const float* b_out    = (const float*)d_in[16];
    const float* gamma    = (const float*)d_in[17];
    float* out = (float*)d_out;

    char* ws = (char*)d_ws;
    unsigned short* WtV   = (unsigned short*)(ws);
    unsigned short* WtO   = (unsigned short*)(ws + 131072);
    unsigned short* WtC   = (unsigned short*)(ws + 262144);
    unsigned short* value = (unsigned short*)(ws + 311296);
    float4*        samples = (float4*)(ws + 311296 + 33554432);
    unsigned short* accb  = (unsigned short*)(ws + 311296 + 67108864);

    hipLaunchKernelGGL(k_prep, dim3(608), dim3(256), 0, stream,
                       W_value, W_off, W_attn, W_out, WtV, WtC, WtO);
    hipLaunchKernelGGL(k_ln_value, dim3(1024), dim3(256), 0, stream,
                       feat, fn_scale, fn_bias, b_value, WtV, value);
    hipLaunchKernelGGL(k_ln_qoff, dim3(1024), dim3(256), 0, stream,
                       query, qn_scale, qn_bias, refpt, b_off, b_attn, WtC, samples);
    hipLaunchKernelGGL(k_gather, dim3(8192), dim3(256), 0, stream,
                       value, samples, accb);
    hipLaunchKernelGGL(k_out, dim3(512), dim3(256), 0, stream,
                       accb, WtO, b_out, gamma, query, out);
}

// Round 4
// 177.835 us; speedup vs baseline: 2.2677x; 1.3726x over previous
//
#include <hip/hip_runtime.h>

#define NQ 16384
#define NV 16384
#define DMODEL 256

typedef __bf16 bf16x8 __attribute__((ext_vector_type(8)));
typedef float f32x4 __attribute__((ext_vector_type(4)));

__device__ __forceinline__ unsigned short f2bf(float x) {
    union { float f; unsigned int u; } v; v.f = x;
    unsigned int r = v.u + 0x7fff + ((v.u >> 16) & 1);
    return (unsigned short)(r >> 16);
}
__device__ __forceinline__ float blo(unsigned int u) {
    union { unsigned int u; float f; } v; v.u = u << 16; return v.f;
}
__device__ __forceinline__ float bhi(unsigned int u) {
    union { unsigned int u; float f; } v; v.u = u & 0xFFFF0000u; return v.f;
}
__device__ __forceinline__ f32x4 mfma16(bf16x8 a, bf16x8 b, f32x4 c) {
    return __builtin_amdgcn_mfma_f32_16x16x32_bf16(a, b, c, 0, 0, 0);
}

// LN-stage 16 rows (4 quad-steps) into A (ushort stride 264).
// 16-lane row groups: g=lane>>4 picks row-in-quad, li=lane&15 owns 16 floats.
__device__ __forceinline__ void ln_stage_half(
    const float* __restrict__ src, const float4* sc, const float4* bi,
    unsigned short* A, int g_row0, int l_row0, int g, int li) {
    float4 x[4][4];
#pragma unroll
    for (int it = 0; it < 4; ++it) {
        const size_t row = (size_t)(g_row0 + it * 4 + g);
#pragma unroll
        for (int j = 0; j < 4; ++j)
            x[it][j] = *(const float4*)(src + row * 256 + li * 16 + j * 4);
    }
#pragma unroll
    for (int it = 0; it < 4; ++it) {
        float s = 0.f, sq = 0.f;
#pragma unroll
        for (int j = 0; j < 4; ++j) {
            s  += x[it][j].x + x[it][j].y + x[it][j].z + x[it][j].w;
            sq += x[it][j].x * x[it][j].x + x[it][j].y * x[it][j].y +
                  x[it][j].z * x[it][j].z + x[it][j].w * x[it][j].w;
        }
#pragma unroll
        for (int d = 1; d < 16; d <<= 1) {
            s  += __shfl_xor(s, d);
            sq += __shfl_xor(sq, d);
        }
        float mu = s * 0.00390625f;
        float rstd = rsqrtf(sq * 0.00390625f - mu * mu + 1e-6f);
        unsigned int pk[8];
#pragma unroll
        for (int j = 0; j < 4; ++j) {
            pk[2 * j] = (unsigned)f2bf((x[it][j].x - mu) * rstd * sc[j].x + bi[j].x) |
                        ((unsigned)f2bf((x[it][j].y - mu) * rstd * sc[j].y + bi[j].y) << 16);
            pk[2 * j + 1] = (unsigned)f2bf((x[it][j].z - mu) * rstd * sc[j].z + bi[j].z) |
                            ((unsigned)f2bf((x[it][j].w - mu) * rstd * sc[j].w + bi[j].w) << 16);
        }
        uint4* dst = (uint4*)&A[(l_row0 + it * 4 + g) * 264 + li * 16];
        dst[0] = make_uint4(pk[0], pk[1], pk[2], pk[3]);
        dst[1] = make_uint4(pk[4], pk[5], pk[6], pk[7]);
    }
}

// ---------------- prep: transpose weights to bf16 [n][k] ----------------
__global__ __launch_bounds__(256) void k_prep(
    const float* __restrict__ Wv, const float* __restrict__ Woff,
    const float* __restrict__ Wattn, const float* __restrict__ Wout,
    unsigned short* __restrict__ WtV, unsigned short* __restrict__ WtC,
    unsigned short* __restrict__ WtO) {
    int t = blockIdx.x * 256 + threadIdx.x;
    if (t < 256 * 256) { int n = t >> 8, k = t & 255; WtV[t] = f2bf(Wv[k * 256 + n]); return; }
    t -= 256 * 256;
    if (t < 256 * 256) { int n = t >> 8, k = t & 255; WtO[t] = f2bf(Wout[k * 256 + n]); return; }
    t -= 256 * 256;
    if (t < 96 * 256) {
        int j = t >> 8, k = t & 255;
        float w = (j < 64) ? Woff[k * 64 + j] : Wattn[k * 32 + (j - 64)];
        WtC[j * 256 + k] = f2bf(w);
    }
}

// ---------------- LN(feat) + value GEMM (M=128, nt-split, swapped-D) ----------------
__global__ __launch_bounds__(256) void k_ln_value(
    const float* __restrict__ feat, const float* __restrict__ fn_scale,
    const float* __restrict__ fn_bias, const float* __restrict__ b_value,
    const unsigned short* __restrict__ WtV, unsigned short* __restrict__ value) {
    __shared__ unsigned short A[128 * 264];
    const int lane = threadIdx.x & 63;
    const int w = threadIdx.x >> 6;
    const int m0 = blockIdx.x * 128;
    const int g = lane >> 4, li = lane & 15;
    {
        float4 sc[4], bi[4];
#pragma unroll
        for (int j = 0; j < 4; ++j) {
            sc[j] = *(const float4*)(fn_scale + li * 16 + j * 4);
            bi[j] = *(const float4*)(fn_bias + li * 16 + j * 4);
        }
        ln_stage_half(feat, sc, bi, A, m0 + w * 32, w * 32, g, li);
        ln_stage_half(feat, sc, bi, A, m0 + w * 32 + 16, w * 32 + 16, g, li);
    }
    __syncthreads();
    const int lrow = lane & 15, lk = (lane >> 4) * 8;
    f32x4 acc[4][8];
#pragma unroll
    for (int i = 0; i < 4; ++i)
#pragma unroll
        for (int m = 0; m < 8; ++m) acc[i][m] = (f32x4){0.f, 0.f, 0.f, 0.f};

#define LOADB_V(dst, kk)                                                              \
    _Pragma("unroll") for (int i = 0; i < 4; ++i) dst[i] =                            \
        *(const bf16x8*)(WtV + (size_t)((w * 4 + i) * 16 + lrow) * 256 + (kk) * 32 + lk);
#define MFMA_STEP_V(bf, kk)                                                           \
    _Pragma("unroll") for (int m = 0; m < 8; ++m) {                                   \
        bf16x8 a = *(const bf16x8*)&A[(m * 16 + lrow) * 264 + (kk) * 32 + lk];        \
        _Pragma("unroll") for (int i = 0; i < 4; ++i)                                 \
            acc[i][m] = mfma16(bf[i], a, acc[i][m]);                                  \
    }
    {
        bf16x8 b0[4], b1[4];
        LOADB_V(b0, 0)
#pragma unroll
        for (int k2 = 0; k2 < 4; ++k2) {
            LOADB_V(b1, k2 * 2 + 1)
            MFMA_STEP_V(b0, k2 * 2)
            if (k2 < 3) { LOADB_V(b0, k2 * 2 + 2) }
            MFMA_STEP_V(b1, k2 * 2 + 1)
        }
    }
#pragma unroll
    for (int i = 0; i < 4; ++i) {
        const int col0 = (w * 4 + i) * 16 + (lane >> 4) * 4;
        float4 bv = *(const float4*)(b_value + col0);
#pragma unroll
        for (int m = 0; m < 8; ++m) {
            const size_t row = (size_t)(m0 + m * 16 + (lane & 15));
            uint2 r;
            r.x = (unsigned)f2bf(acc[i][m][0] + bv.x) | ((unsigned)f2bf(acc[i][m][1] + bv.y) << 16);
            r.y = (unsigned)f2bf(acc[i][m][2] + bv.z) | ((unsigned)f2bf(acc[i][m][3] + bv.w) << 16);
            *(uint2*)(value + row * 256 + col0) = r;
        }
    }
}

// ---------------- LN(query) + off/attn GEMM + softmax (M=128) ----------------
__global__ __launch_bounds__(256) void k_ln_qoff(
    const float* __restrict__ query, const float* __restrict__ qn_scale,
    const float* __restrict__ qn_bias, const float* __restrict__ refpt,
    const float* __restrict__ b_off, const float* __restrict__ b_attn,
    const unsigned short* __restrict__ WtC, float4* __restrict__ samples) {
    __shared__ unsigned short A[128 * 264];
    const int lane = threadIdx.x & 63;
    const int w = threadIdx.x >> 6;
    const int m0 = blockIdx.x * 128;
    const int g = lane >> 4, li = lane & 15;
    {
        float4 sc[4], bi[4];
#pragma unroll
        for (int j = 0; j < 4; ++j) {
            sc[j] = *(const float4*)(qn_scale + li * 16 + j * 4);
            bi[j] = *(const float4*)(qn_bias + li * 16 + j * 4);
        }
        ln_stage_half(query, sc, bi, A, m0 + w * 32, w * 32, g, li);
        ln_stage_half(query, sc, bi, A, m0 + w * 32 + 16, w * 32 + 16, g, li);
    }
    __syncthreads();
    const int lrow = lane & 15, lk = (lane >> 4) * 8;
    f32x4 acc[6][2];
#pragma unroll
    for (int i = 0; i < 6; ++i)
#pragma unroll
        for (int m = 0; m < 2; ++m) acc[i][m] = (f32x4){0.f, 0.f, 0.f, 0.f};

#define LOADB_Q(dst, kk)                                                              \
    _Pragma("unroll") for (int i = 0; i < 6; ++i) dst[i] =                            \
        *(const bf16x8*)(WtC + (size_t)(i * 16 + lrow) * 256 + (kk) * 32 + lk);
#define MFMA_STEP_Q(bf, kk)                                                           \
    _Pragma("unroll") for (int m = 0; m < 2; ++m) {                                   \
        bf16x8 a = *(const bf16x8*)&A[(w * 32 + m * 16 + lrow) * 264 + (kk) * 32 + lk]; \
        _Pragma("unroll") for (int i = 0; i < 6; ++i)                                 \
            acc[i][m] = mfma16(bf[i], a, acc[i][m]);                                  \
    }
    {
        bf16x8 b0[6], b1[6];
        LOADB_Q(b0, 0)
#pragma unroll
        for (int k2 = 0; k2 < 4; ++k2) {
            LOADB_Q(b1, k2 * 2 + 1)
            MFMA_STEP_Q(b0, k2 * 2)
            if (k2 < 3) { LOADB_Q(b0, k2 * 2 + 2) }
            MFMA_STEP_Q(b1, k2 * 2 + 1)
        }
    }
    __syncthreads();
    // per-wave D buffer in A's region: 32 rows x 96 cols fp32, stride 100 (bank stagger)
    float* Dl = (float*)A + w * 4224;
#pragma unroll
    for (int i = 0; i < 6; ++i) {
        const int col0 = i * 16 + (lane >> 4) * 4;
#pragma unroll
        for (int m = 0; m < 2; ++m) {
            const int rl = m * 16 + (lane & 15);
            *(float4*)&Dl[rl * 100 + col0] =
                make_float4(acc[i][m][0], acc[i][m][1], acc[i][m][2], acc[i][m][3]);
        }
    }
    __syncthreads();
#pragma unroll
    for (int it = 0; it < 4; ++it) {
        int idx = it * 64 + lane;     // 32 rows x 8 heads
        int rl = idx >> 3;
        int h = idx & 7;
        int row = m0 + w * 32 + rl;
        float rx = refpt[(size_t)row * 2 + 0] * 128.f - 0.5f;
        float ry = refpt[(size_t)row * 2 + 1] * 128.f - 0.5f;
        float l0 = Dl[rl * 100 + 64 + h * 4 + 0] + b_attn[h * 4 + 0];
        float l1 = Dl[rl * 100 + 64 + h * 4 + 1] + b_attn[h * 4 + 1];
        float l2 = Dl[rl * 100 + 64 + h * 4 + 2] + b_attn[h * 4 + 2];
        float l3 = Dl[rl * 100 + 64 + h * 4 + 3] + b_attn[h * 4 + 3];
        float mx = fmaxf(fmaxf(l0, l1), fmaxf(l2, l3));
        float e0 = __expf(l0 - mx), e1 = __expf(l1 - mx);
        float e2 = __expf(l2 - mx), e3 = __expf(l3 - mx);
        float inv = 1.f / (e0 + e1 + e2 + e3);
        float ww[4] = {e0 * inv, e1 * inv, e2 * inv, e3 * inv};
#pragma unroll
        for (int p = 0; p < 4; ++p) {
            float ox = Dl[rl * 100 + h * 8 + p * 2 + 0] + b_off[h * 8 + p * 2 + 0];
            float oy = Dl[rl * 100 + h * 8 + p * 2 + 1] + b_off[h * 8 + p * 2 + 1];
            samples[((size_t)row * 8 + h) * 4 + p] = make_float4(rx + ox, ry + oy, ww[p], 0.f);
        }
    }
}

// ---------------- bilinear gather + attention-weighted sum -> bf16 acc ----------------
__global__ __launch_bounds__(256) void k_gather(
    const unsigned short* __restrict__ value, const float4* __restrict__ samples,
    unsigned short* __restrict__ accb) {
    const int tid = blockIdx.x * 256 + threadIdx.x;
    const int sub = tid & 3;         // channel-quad (8 channels)
    const int t = tid >> 2;          // (b*NQ+q)*8 + h
    const int h = t & 7;
    const int bq = t >> 3;
    const int b = bq >> 14;
    const unsigned short* vb = value + ((size_t)b << 14) * 256 + h * 32 + sub * 8;
    float a0 = 0.f, a1 = 0.f, a2 = 0.f, a3 = 0.f;
    float a4 = 0.f, a5 = 0.f, a6 = 0.f, a7 = 0.f;
#pragma unroll
    for (int p = 0; p < 4; ++p) {
        float4 s = samples[(size_t)t * 4 + p];
        float xf = floorf(s.x), yf = floorf(s.y);
        float fx = s.x - xf, fy = s.y - yf;
        int x0 = (int)xf, y0 = (int)yf;
        int x1 = x0 + 1, y1 = y0 + 1;
        float wgt = s.z;
        bool bx0 = (unsigned)x0 < 128u, bx1 = (unsigned)x1 < 128u;
        bool by0 = (unsigned)y0 < 128u, by1 = (unsigned)y1 < 128u;
        float wt[4];
        wt[0] = (bx0 && by0) ? (1.f - fx) * (1.f - fy) * wgt : 0.f;
        wt[1] = (bx1 && by0) ? fx * (1.f - fy) * wgt : 0.f;
        wt[2] = (bx0 && by1) ? (1.f - fx) * fy * wgt : 0.f;
        wt[3] = (bx1 && by1) ? fx * fy * wgt : 0.f;
        int xc0 = min(max(x0, 0), 127), xc1 = min(max(x1, 0), 127);
        int yc0 = min(max(y0, 0), 127), yc1 = min(max(y1, 0), 127);
        int pix[4];
        pix[0] = yc0 * 128 + xc0; pix[1] = yc0 * 128 + xc1;
        pix[2] = yc1 * 128 + xc0; pix[3] = yc1 * 128 + xc1;
#pragma unroll
        for (int tp = 0; tp < 4; ++tp) {
            uint4 u = *(const uint4*)(vb + (size_t)pix[tp] * 256);
            float w = wt[tp];
            a0 = fmaf(w, blo(u.x), a0); a1 = fmaf(w, bhi(u.x), a1);
            a2 = fmaf(w, blo(u.y), a2); a3 = fmaf(w, bhi(u.y), a3);
            a4 = fmaf(w, blo(u.z), a4); a5 = fmaf(w, bhi(u.z), a5);
            a6 = fmaf(w, blo(u.w), a6); a7 = fmaf(w, bhi(u.w), a7);
        }
    }
    uint4 r;
    r.x = (unsigned)f2bf(a0) | ((unsigned)f2bf(a1) << 16);
    r.y = (unsigned)f2bf(a2) | ((unsigned)f2bf(a3) << 16);
    r.z = (unsigned)f2bf(a4) | ((unsigned)f2bf(a5) << 16);
    r.w = (unsigned)f2bf(a6) | ((unsigned)f2bf(a7) << 16);
    *(uint4*)(accb + (size_t)bq * 256 + h * 32 + sub * 8) = r;
}

// ---------------- out GEMM + bias + gated residual (M=128, nt-split, swapped-D) ----------------
__global__ __launch_bounds__(256) void k_out(
    const unsigned short* __restrict__ accb, const unsigned short* __restrict__ WtO,
    const float* __restrict__ b_out, const float* __restrict__ gamma,
    const float* __restrict__ query, float* __restrict__ out) {
    __shared__ unsigned short A[128 * 264];
    const int m0 = blockIdx.x * 128;
    {
        const int c = threadIdx.x & 31;
        const int r0 = threadIdx.x >> 5;
#pragma unroll
        for (int i = 0; i < 16; ++i) {
            const int r = r0 + i * 8;
            *(uint4*)&A[r * 264 + c * 8] = *(const uint4*)(accb + (size_t)(m0 + r) * 256 + c * 8);
        }
    }
    __syncthreads();
    const int lane = threadIdx.x & 63;
    const int w = threadIdx.x >> 6;
    const int lrow = lane & 15, lk = (lane >> 4) * 8;
    f32x4 acc[4][8];
#pragma unroll
    for (int i = 0; i < 4; ++i)
#pragma unroll
        for (int m = 0; m < 8; ++m) acc[i][m] = (f32x4){0.f, 0.f, 0.f, 0.f};

#define LOADB_O(dst, kk)                                                              \
    _Pragma("unroll") for (int i = 0; i < 4; ++i) dst[i] =                            \
        *(const bf16x8*)(WtO + (size_t)((w * 4 + i) * 16 + lrow) * 256 + (kk) * 32 + lk);
    {
        bf16x8 b0[4], b1[4];
        LOADB_O(b0, 0)
#pragma unroll
        for (int k2 = 0; k2 < 4; ++k2) {
            LOADB_O(b1, k2 * 2 + 1)
            MFMA_STEP_V(b0, k2 * 2)
            if (k2 < 3) { LOADB_O(b0, k2 * 2 + 2) }
            MFMA_STEP_V(b1, k2 * 2 + 1)
        }
    }
#pragma unroll
    for (int i = 0; i < 4; ++i) {
        const int col0 = (w * 4 + i) * 16 + (lane >> 4) * 4;
        float4 bo = *(const float4*)(b_out + col0);
        float4 gm = *(const float4*)(gamma + col0);
#pragma unroll
        for (int m = 0; m < 8; ++m) {
            const size_t row = (size_t)(m0 + m * 16 + (lane & 15));
            float4 q = *(const float4*)(query + row * 256 + col0);
            float4 o;
            o.x = q.x + gm.x * (acc[i][m][0] + bo.x);
            o.y = q.y + gm.y * (acc[i][m][1] + bo.y);
            o.z = q.z + gm.z * (acc[i][m][2] + bo.z);
            o.w = q.w + gm.w * (acc[i][m][3] + bo.w);
            *(float4*)(out + row * 256 + col0) = o;
        }
    }
}

extern "C" void kernel_launch(void* const* d_in, const int* in_sizes, int n_in,
                              void* d_out, int out_size, void* d_ws, size_t ws_size,
                              hipStream_t stream) {
    const float* query    = (const float*)d_in[0];
    const float* feat     = (const float*)d_in[1];
    const float* refpt    = (const float*)d_in[2];
    const float* qn_scale = (const float*)d_in[5];
    const float* qn_bias  = (const float*)d_in[6];
    const float* fn_scale = (const float*)d_in[7];
    const float* fn_bias  = (const float*)d_in[8];
    const float* W_value  = (const float*)d_in[9];
    const float* b_value  = (const float*)d_in[10];
    const float* W_off    = (const float*)d_in[11];
    const float* b_off    = (const float*)d_in[12];
    const float* W_attn   = (const float*)d_in[13];
    const float* b_attn   = (const float*)d_in[14];
    const float* W_out    = (const float*)d_in[15];
    const float* b_out    = (const float*)d_in[16];
    const float* gamma    = (const float*)d_in[17];
    float* out = (float*)d_out;

    char* ws = (char*)d_ws;
    unsigned short* WtV   = (unsigned short*)(ws);
    unsigned short* WtO   = (unsigned short*)(ws + 131072);
    unsigned short* WtC   = (unsigned short*)(ws + 262144);
    unsigned short* value = (unsigned short*)(ws + 311296);
    float4*        samples = (float4*)(ws + 311296 + 33554432);
    unsigned short* accb  = (unsigned short*)(ws + 311296 + 67108864);

    hipLaunchKernelGGL(k_prep, dim3(608), dim3(256), 0, stream,
                       W_value, W_off, W_attn, W_out, WtV, WtC, WtO);
    hipLaunchKernelGGL(k_ln_value, dim3(512), dim3(256), 0, stream,
                       feat, fn_scale, fn_bias, b_value, WtV, value);
    hipLaunchKernelGGL(k_ln_qoff, dim3(512), dim3(256), 0, stream,
                       query, qn_scale, qn_bias, refpt, b_off, b_attn, WtC, samples);
    hipLaunchKernelGGL(k_gather, dim3(8192), dim3(256), 0, stream,
                       value, samples, accb);
    hipLaunchKernelGGL(k_out, dim3(512), dim3(256), 0, stream,
                       accb, WtO, b_out, gamma, query, out);
}